// Round 2
// baseline (48.706 us; speedup 1.0000x reference)
//
#include <hip/hip_runtime.h>
#include <hip/hip_bf16.h>

// PatchIoULoss: B=16, C=1, H=W=1024, patch 64x64, stride 32x32 -> Ho=Wo=31.
// Window(i,j) = sum of 2x2 group of non-overlapping 32x32 block sums.

#define Hdim 1024
#define Wdim 1024
#define NBLK 32          // 32x32 blocks per image per dim
#define HO 31
#define WO 31
#define EPSF 1e-7f

// Kernel 1: per-block(32x32) sums of pred, target, pred*target.
// grid = B * 32 strips * 4 column-quarters = 2048 blocks; 256 threads each
// (= 8192 waves = full machine). Block (b, strip, q) covers rows
// [strip*32, strip*32+32) x float4-cols [q*64, q*64+64).
// Iteration i: thread t reads row 4i + (t>>6), float4-col (t&63) of the
// quarter -> each wave reads 1 KiB contiguous. Column-tile of a lane is
// (t&63)>>3 (8 lanes per 32-col tile) -> 8-lane shuffle reduce, then a
// tiny LDS reduce across the 4 waves yields full 32x32 block sums.
__global__ __launch_bounds__(256) void block_sums_kernel(
    const float* __restrict__ pred, const float* __restrict__ targ,
    float* __restrict__ sp, float* __restrict__ st, float* __restrict__ si) {
    const int blk = blockIdx.x;
    const int q = blk & 3;           // column quarter 0..3
    const int strip = (blk >> 2) & 31;
    const int b = blk >> 7;          // image
    const int t = threadIdx.x;       // 0..255
    const int wid = t >> 6;          // wave 0..3
    const int lane = t & 63;

    const float4* __restrict__ p4 =
        reinterpret_cast<const float4*>(pred) + (size_t)b * (Hdim * Wdim / 4)
        + (size_t)strip * 32 * (Wdim / 4) + q * 64;
    const float4* __restrict__ g4 =
        reinterpret_cast<const float4*>(targ) + (size_t)b * (Hdim * Wdim / 4)
        + (size_t)strip * 32 * (Wdim / 4) + q * 64;

    float s_p = 0.f, s_t = 0.f, s_i = 0.f;
#pragma unroll
    for (int i = 0; i < 8; ++i) {
        const int idx = (4 * i + wid) * (Wdim / 4) + lane;
        float4 p = p4[idx];
        float4 g = g4[idx];
        s_p += (p.x + p.y) + (p.z + p.w);
        s_t += (g.x + g.y) + (g.z + g.w);
        s_i += p.x * g.x + p.y * g.y + p.z * g.z + p.w * g.w;
    }
    // Reduce the 8 lanes of each column-tile (lanes 8k..8k+7, same wave).
#pragma unroll
    for (int off = 4; off >= 1; off >>= 1) {
        s_p += __shfl_down(s_p, off, 64);
        s_t += __shfl_down(s_t, off, 64);
        s_i += __shfl_down(s_i, off, 64);
    }
    // Cross-wave reduce: 4 waves x 8 tiles per quantity.
    __shared__ float redp[4][8], redt[4][8], redi[4][8];
    if ((lane & 7) == 0) {
        const int tile = lane >> 3;  // 0..7
        redp[wid][tile] = s_p;
        redt[wid][tile] = s_t;
        redi[wid][tile] = s_i;
    }
    __syncthreads();
    if (t < 8) {
        const int idx = b * (NBLK * NBLK) + strip * NBLK + q * 8 + t;
        sp[idx] = (redp[0][t] + redp[1][t]) + (redp[2][t] + redp[3][t]);
        st[idx] = (redt[0][t] + redt[1][t]) + (redt[2][t] + redt[3][t]);
        si[idx] = (redi[0][t] + redi[1][t]) + (redi[2][t] + redi[3][t]);
    }
}

// Kernel 2: combine 2x2 block sums per window, compute loss, mean over all.
// Single block of 256 threads; B*31*31 = 15376 windows.
__global__ __launch_bounds__(256) void finalize_kernel(
    const float* __restrict__ sp, const float* __restrict__ st,
    const float* __restrict__ si, float* __restrict__ out, int B) {
    const int t = threadIdx.x;
    const int nwin = B * HO * WO;
    float acc = 0.f;
    for (int w = t; w < nwin; w += 256) {
        const int b = w / (HO * WO);
        const int rem = w - b * (HO * WO);
        const int i = rem / WO;
        const int j = rem - i * WO;
        const int base = b * (NBLK * NBLK) + i * NBLK + j;
        const float inter = (si[base] + si[base + 1]) + (si[base + NBLK] + si[base + NBLK + 1]);
        const float psum  = (sp[base] + sp[base + 1]) + (sp[base + NBLK] + sp[base + NBLK + 1]);
        const float tsum  = (st[base] + st[base + 1]) + (st[base + NBLK] + st[base + NBLK + 1]);
        const float uni = psum + tsum - inter;
        acc += 1.0f - (inter + EPSF) / (uni + EPSF);
    }
    // wave reduce
#pragma unroll
    for (int off = 32; off >= 1; off >>= 1) acc += __shfl_down(acc, off, 64);
    __shared__ float red[4];
    if ((t & 63) == 0) red[t >> 6] = acc;
    __syncthreads();
    if (t == 0) {
        const float s = (red[0] + red[1]) + (red[2] + red[3]);
        out[0] = s / (float)nwin;
    }
}

extern "C" void kernel_launch(void* const* d_in, const int* in_sizes, int n_in,
                              void* d_out, int out_size, void* d_ws, size_t ws_size,
                              hipStream_t stream) {
    const float* pred = (const float*)d_in[0];
    const float* targ = (const float*)d_in[1];
    float* out = (float*)d_out;

    const int B = in_sizes[0] / (Hdim * Wdim);   // 16
    const int nblocks = B * NBLK * NBLK;         // block sums per quantity

    float* sp = (float*)d_ws;
    float* st = sp + nblocks;
    float* si = st + nblocks;

    block_sums_kernel<<<dim3(B * 32 * 4), dim3(256), 0, stream>>>(pred, targ, sp, st, si);
    finalize_kernel<<<dim3(1), dim3(256), 0, stream>>>(sp, st, si, out, B);
}

// Round 4
// 37.271 us; speedup vs baseline: 1.3068x; 1.3068x over previous
//
#include <hip/hip_runtime.h>
#include <hip/hip_bf16.h>

// PatchIoULoss: B=16, C=1, H=W=1024, patch 64x64, stride 32x32 -> Ho=Wo=31.
// Window(i,j) = sum of 2x2 group of non-overlapping 32x32 block sums.

#define Hdim 1024
#define Wdim 1024
#define NBLK 32          // 32x32 blocks per image per dim
#define HO 31
#define WO 31
#define EPSF 1e-7f

typedef float fx4 __attribute__((ext_vector_type(4)));

// Kernel 1: per-block(32x32) sums of pred, target, pred*target.
// grid = B * 32 strips * 4 column-quarters = 2048 blocks; 256 threads each.
// Loads are NONTEMPORAL: pred/targ are two 64-MiB streams at identical
// offsets -> they alias in L2/L3 sets; nt bypasses allocation and streams
// both at HBM rate instead of thrashing.
__global__ __launch_bounds__(256) void block_sums_kernel(
    const float* __restrict__ pred, const float* __restrict__ targ,
    float* __restrict__ sp, float* __restrict__ st, float* __restrict__ si) {
    const int blk = blockIdx.x;
    const int q = blk & 3;           // column quarter 0..3
    const int strip = (blk >> 2) & 31;
    const int b = blk >> 7;          // image
    const int t = threadIdx.x;       // 0..255
    const int wid = t >> 6;          // wave 0..3
    const int lane = t & 63;

    const fx4* __restrict__ p4 =
        reinterpret_cast<const fx4*>(pred) + (size_t)b * (Hdim * Wdim / 4)
        + (size_t)strip * 32 * (Wdim / 4) + q * 64;
    const fx4* __restrict__ g4 =
        reinterpret_cast<const fx4*>(targ) + (size_t)b * (Hdim * Wdim / 4)
        + (size_t)strip * 32 * (Wdim / 4) + q * 64;

    float s_p = 0.f, s_t = 0.f, s_i = 0.f;
#pragma unroll
    for (int i = 0; i < 8; ++i) {
        const int idx = (4 * i + wid) * (Wdim / 4) + lane;
        fx4 p = __builtin_nontemporal_load(&p4[idx]);
        fx4 g = __builtin_nontemporal_load(&g4[idx]);
        s_p += (p.x + p.y) + (p.z + p.w);
        s_t += (g.x + g.y) + (g.z + g.w);
        s_i += p.x * g.x + p.y * g.y + p.z * g.z + p.w * g.w;
    }
    // Reduce the 8 lanes of each column-tile (lanes 8k..8k+7, same wave).
#pragma unroll
    for (int off = 4; off >= 1; off >>= 1) {
        s_p += __shfl_down(s_p, off, 64);
        s_t += __shfl_down(s_t, off, 64);
        s_i += __shfl_down(s_i, off, 64);
    }
    // Cross-wave reduce: 4 waves x 8 tiles per quantity.
    __shared__ float redp[4][8], redt[4][8], redi[4][8];
    if ((lane & 7) == 0) {
        const int tile = lane >> 3;  // 0..7
        redp[wid][tile] = s_p;
        redt[wid][tile] = s_t;
        redi[wid][tile] = s_i;
    }
    __syncthreads();
    if (t < 8) {
        const int idx = b * (NBLK * NBLK) + strip * NBLK + q * 8 + t;
        sp[idx] = (redp[0][t] + redp[1][t]) + (redp[2][t] + redp[3][t]);
        st[idx] = (redt[0][t] + redt[1][t]) + (redt[2][t] + redt[3][t]);
        si[idx] = (redi[0][t] + redi[1][t]) + (redi[2][t] + redi[3][t]);
    }
}

// Kernel 2: combine 2x2 block sums per window, compute loss, mean over all.
// Single block of 1024 threads; B*31*31 = 15376 windows (15 iters/thread).
__global__ __launch_bounds__(1024) void finalize_kernel(
    const float* __restrict__ sp, const float* __restrict__ st,
    const float* __restrict__ si, float* __restrict__ out, int B) {
    const int t = threadIdx.x;
    const int nwin = B * HO * WO;
    float acc = 0.f;
    for (int w = t; w < nwin; w += 1024) {
        const int b = w / (HO * WO);
        const int rem = w - b * (HO * WO);
        const int i = rem / WO;
        const int j = rem - i * WO;
        const int base = b * (NBLK * NBLK) + i * NBLK + j;
        const float inter = (si[base] + si[base + 1]) + (si[base + NBLK] + si[base + NBLK + 1]);
        const float psum  = (sp[base] + sp[base + 1]) + (sp[base + NBLK] + sp[base + NBLK + 1]);
        const float tsum  = (st[base] + st[base + 1]) + (st[base + NBLK] + st[base + NBLK + 1]);
        const float uni = psum + tsum - inter;
        acc += 1.0f - (inter + EPSF) / (uni + EPSF);
    }
    // wave reduce
#pragma unroll
    for (int off = 32; off >= 1; off >>= 1) acc += __shfl_down(acc, off, 64);
    __shared__ float red[16];
    if ((t & 63) == 0) red[t >> 6] = acc;
    __syncthreads();
    if (t == 0) {
        float s = 0.f;
#pragma unroll
        for (int k = 0; k < 16; ++k) s += red[k];
        out[0] = s / (float)nwin;
    }
}

extern "C" void kernel_launch(void* const* d_in, const int* in_sizes, int n_in,
                              void* d_out, int out_size, void* d_ws, size_t ws_size,
                              hipStream_t stream) {
    const float* pred = (const float*)d_in[0];
    const float* targ = (const float*)d_in[1];
    float* out = (float*)d_out;

    const int B = in_sizes[0] / (Hdim * Wdim);   // 16
    const int nblocks = B * NBLK * NBLK;         // block sums per quantity

    float* sp = (float*)d_ws;
    float* st = sp + nblocks;
    float* si = st + nblocks;

    block_sums_kernel<<<dim3(B * 32 * 4), dim3(256), 0, stream>>>(pred, targ, sp, st, si);
    finalize_kernel<<<dim3(1), dim3(1024), 0, stream>>>(sp, st, si, out, B);
}